// Round 8
// baseline (2009.982 us; speedup 1.0000x reference)
//
#include <hip/hip_runtime.h>
#include <cstdint>
#include <cstddef>

// Problem constants
constexpr int B = 64, S = 2048, H = 512, E = 256, V = 32000;
constexpr int NCHUNK = 32;   // attention: 32 chunks of 64 keys per batch

// ---------------------------------------------------------------------------
// Kernel 1: fused scores + online-softmax partials (enc read exactly once).
// One wave per (b, 64-key chunk); lane covers 8 of 512 dims (2 float4 slices).
// Software-pipelined key loop (prefetch key s+1 before consuming key s).
// Measured in-situ ~45 us ~= its 43 us HBM floor (R7 ledger) — do not touch.
// ---------------------------------------------------------------------------
__global__ __launch_bounds__(256) void attn_part_kernel(
    const float* __restrict__ hd, const float* __restrict__ enc,
    float* __restrict__ m_part, float* __restrict__ l_part,
    float* __restrict__ acc_part)
{
    int b = blockIdx.x >> 3;
    int wave = threadIdx.x >> 6, lane = threadIdx.x & 63;
    int chunk = ((blockIdx.x & 7) << 2) + wave;
    int s0 = chunk * 64;

    const float4* hv = (const float4*)(hd + (size_t)b * H);
    float4 h0 = hv[lane], h1 = hv[64 + lane];
    const float4* ev = (const float4*)(enc + (size_t)b * S * H) + (size_t)s0 * (H / 4);

    float m = -1e30f, l = 0.f;
    float4 a0 = make_float4(0.f, 0.f, 0.f, 0.f);
    float4 a1 = make_float4(0.f, 0.f, 0.f, 0.f);
    float4 e0 = ev[lane], e1 = ev[64 + lane];

    auto process = [&](const float4& pe0, const float4& pe1) {
        float p = pe0.x * h0.x + pe0.y * h0.y + pe0.z * h0.z + pe0.w * h0.w
                + pe1.x * h1.x + pe1.y * h1.y + pe1.z * h1.z + pe1.w * h1.w;
#pragma unroll
        for (int off = 32; off; off >>= 1) p += __shfl_xor(p, off, 64);
        if (p <= m) {                 // wave-uniform branch
            float w = __expf(p - m);
            l += w;
            a0.x += w * pe0.x; a0.y += w * pe0.y; a0.z += w * pe0.z; a0.w += w * pe0.w;
            a1.x += w * pe1.x; a1.y += w * pe1.y; a1.z += w * pe1.z; a1.w += w * pe1.w;
        } else {
            float sc = __expf(m - p); // first iter: exp(-1e30)=0 -> exact init
            m = p;
            l = l * sc + 1.f;
            a0.x = a0.x * sc + pe0.x; a0.y = a0.y * sc + pe0.y;
            a0.z = a0.z * sc + pe0.z; a0.w = a0.w * sc + pe0.w;
            a1.x = a1.x * sc + pe1.x; a1.y = a1.y * sc + pe1.y;
            a1.z = a1.z * sc + pe1.z; a1.w = a1.w * sc + pe1.w;
        }
    };

    for (int s = 0; s < 63; ++s) {
        const float4* r = ev + (size_t)(s + 1) * (H / 4);
        float4 n0 = r[lane], n1 = r[64 + lane];   // prefetch next key
        process(e0, e1);                          // consume current key
        e0 = n0; e1 = n1;
    }
    process(e0, e1);                              // last key

    int base = b * NCHUNK + chunk;
    if (lane == 0) { m_part[base] = m; l_part[base] = l; }
    float4* ap = (float4*)(acc_part + (size_t)base * H);
    ap[lane] = a0; ap[64 + lane] = a1;
}

// ---------------------------------------------------------------------------
// Kernel 2: combine partials -> ctx; embedding gather; transposed LSTM input
// inp_t[k][b]: [0,256)=xe, [256,768)=ctx, [768,1280)=h0.  (~4 us in situ)
// ---------------------------------------------------------------------------
__global__ __launch_bounds__(256) void combine_kernel(
    const float* __restrict__ m_part, const float* __restrict__ l_part,
    const float* __restrict__ acc_part, const int* __restrict__ x,
    const float* __restrict__ emb, const float* __restrict__ h0,
    float* __restrict__ inp_t)
{
    int b = blockIdx.x, t = threadIdx.x;
    float M = -1e30f;
    for (int i = 0; i < NCHUNK; ++i) M = fmaxf(M, m_part[b * NCHUNK + i]);
    float L = 0.f;
    for (int i = 0; i < NCHUNK; ++i)
        L += l_part[b * NCHUNK + i] * __expf(m_part[b * NCHUNK + i] - M);
    float invL = 1.f / L;

    for (int d = t; d < H; d += 256) {
        float s = 0.f;
        for (int i = 0; i < NCHUNK; ++i)
            s += __expf(m_part[b * NCHUNK + i] - M) *
                 acc_part[((size_t)(b * NCHUNK + i)) * H + d];
        inp_t[(E + d) * B + b] = s * invL;
    }
    inp_t[t * B + b] = emb[(size_t)x[b] * E + t];
    for (int d = t; d < H; d += 256)
        inp_t[(E + H + d) * B + b] = h0[b * H + d];
}

// ---------------------------------------------------------------------------
// Kernel 3: fully-fused LSTM layer (round-5 proven version; ~5.5 us/layer).
// ---------------------------------------------------------------------------
__global__ __launch_bounds__(256) void lstm_fused_kernel(
    const float* __restrict__ A1, int lda1, int k1len,
    const float* __restrict__ A2, int lda2, int KT,
    const float* __restrict__ X,
    const float* __restrict__ b_ih, const float* __restrict__ b_hh,
    const float* __restrict__ c_prev,
    float* __restrict__ h_t, float* __restrict__ out_h, float* __restrict__ out_c)
{
    __shared__ float sm[4 * 32 * 20 + 4 * 32 * 64];   // As | Xs  (42.5 KB)
    float (*As)[32][20] = (float(*)[32][20])sm;
    float (*Xs)[32][64] = (float(*)[32][64])(sm + 4 * 32 * 20);
    float (*Ps)[16][64] = (float(*)[16][64])(sm + 4 * 32 * 20); // aliases Xs

    const int t = threadIdx.x;
    const int j0 = blockIdx.x * 4;
    const int QK = KT >> 2;
    const int nIter = QK >> 5;
    const int kq = t >> 6, r = t & 63, ty = r >> 4, tx = r & 15;

    float acc[4][4];
#pragma unroll
    for (int i = 0; i < 4; ++i)
#pragma unroll
        for (int j = 0; j < 4; ++j) acc[i][j] = 0.f;

    for (int it = 0; it < nIter; ++it) {
#pragma unroll
        for (int q = 0; q < 2; ++q) {
            int p = t + q * 256;
            int il = p >> 5, c = p & 31;
            int akq = c >> 3, k4 = (c & 7) * 4;
            int gk = akq * QK + it * 32 + k4;
            int grow = j0 + (il & 3) + 512 * (il >> 2);
            const float* src = (gk < k1len)
                ? A1 + (size_t)grow * lda1 + gk
                : A2 + (size_t)grow * lda2 + (gk - k1len);
            float4 v = *(const float4*)src;
            As[akq][k4 + 0][il] = v.x; As[akq][k4 + 1][il] = v.y;
            As[akq][k4 + 2][il] = v.z; As[akq][k4 + 3][il] = v.w;
        }
#pragma unroll
        for (int q = 0; q < 8; ++q) {
            int p = t + q * 256;
            int kk_all = p >> 4, col = (p & 15) * 4;
            int xkq = kk_all >> 5, kk = kk_all & 31;
            int gk = xkq * QK + it * 32 + kk;
            *(float4*)&Xs[xkq][kk][col] = *(const float4*)&X[(size_t)gk * 64 + col];
        }
        __syncthreads();

#pragma unroll 8
        for (int kk = 0; kk < 32; ++kk) {
            float4 av = *(const float4*)&As[kq][kk][ty * 4];
            float4 xv = *(const float4*)&Xs[kq][kk][tx * 4];
            float aa[4] = {av.x, av.y, av.z, av.w};
            float xx[4] = {xv.x, xv.y, xv.z, xv.w};
#pragma unroll
            for (int i = 0; i < 4; ++i)
#pragma unroll
                for (int j = 0; j < 4; ++j) acc[i][j] += aa[i] * xx[j];
        }
        __syncthreads();
    }

#pragma unroll
    for (int i = 0; i < 4; ++i)
        *(float4*)&Ps[kq][ty * 4 + i][tx * 4] =
            make_float4(acc[i][0], acc[i][1], acc[i][2], acc[i][3]);
    __syncthreads();

    for (int idx = t; idx < 16 * 64; idx += 256) {
        int row = idx >> 6, b = idx & 63;
        Ps[0][row][b] = Ps[0][row][b] + Ps[1][row][b] + Ps[2][row][b] + Ps[3][row][b];
    }
    __syncthreads();

    {
        int jj = t >> 6, b = t & 63;
        int j = j0 + jj;
        float gi = Ps[0][jj][b]      + b_ih[j]        + b_hh[j];
        float gf = Ps[0][4 + jj][b]  + b_ih[j + 512]  + b_hh[j + 512];
        float gg = Ps[0][8 + jj][b]  + b_ih[j + 1024] + b_hh[j + 1024];
        float go = Ps[0][12 + jj][b] + b_ih[j + 1536] + b_hh[j + 1536];
        float iv = 1.f / (1.f + __expf(-gi));
        float fv = 1.f / (1.f + __expf(-gf));
        float gv = tanhf(gg);
        float ov = 1.f / (1.f + __expf(-go));
        float cp = c_prev ? c_prev[b * H + j] : 0.f;
        float c2 = fv * cp + iv * gv;
        float hv = ov * tanhf(c2);
        h_t[j * B + b] = hv;
        if (out_h) { out_h[b * H + j] = hv; out_c[b * H + j] = c2; }
    }
}

// ---------------------------------------------------------------------------
// Kernel 4 (v4): fc logits = z^T @ fc_w^T + fc_b.
// A (fc_w, zero reuse) streamed global->reg exactly once. Fixes vs v3 (108us,
// VALUBusy 51%, Occ 11.7%):
//  - NO register copies: 4 rotating prefetch buffers, fully-static indexing
//    (consume bufs[j] at group g, reload with group g+4 -> distance 4 groups).
//  - TM=4/BM=32/1000 blocks, Xs phase tile 32 KB, __launch_bounds__(256,4)
//    -> 4 blocks/CU = 16 waves/CU (2x TLP) and VGPR <= 128.
// Thread (tx,ty): cols 2tx,2tx+1; rows m0+4ty..+3. 32 FMA per 4-k group.
// ---------------------------------------------------------------------------
__global__ __launch_bounds__(256, 4) void fc_gemm_kernel(
    const float* __restrict__ A, const float* __restrict__ X,
    float* __restrict__ outp, const float* __restrict__ bias)
{
    __shared__ float Xs[128][64];          // 32 KB phase tile of X

    const int t = threadIdx.x;
    const int tx = t & 31;                 // col pair: 2tx, 2tx+1
    const int ty = t >> 5;                 // row group: m0+4ty .. +3
    const int m0 = blockIdx.x * 32;
    const float* Arow = A + (size_t)(m0 + ty * 4) * 512;

    float acc[4][2];
#pragma unroll
    for (int i = 0; i < 4; ++i) { acc[i][0] = 0.f; acc[i][1] = 0.f; }

    // 4 rotating A-prefetch buffers; bufs[j] holds 4-k group (4j .. 4j+3) of
    // each of this thread's 4 rows. All indices compile-time constant.
    float4 bufs[4][4];
#pragma unroll
    for (int j = 0; j < 4; ++j)
#pragma unroll
        for (int i = 0; i < 4; ++i)
            bufs[j][i] = *(const float4*)(Arow + (size_t)i * 512 + j * 4);

    for (int ph = 0; ph < 4; ++ph) {
        __syncthreads();                   // prev phase fully consumed
        // stage X phase tile: k rows ph*128 .. +127 (8 float4 per thread)
#pragma unroll
        for (int q = 0; q < 8; ++q) {
            int p = t + q * 256;
            int row = p >> 4, col = (p & 15) * 4;
            *(float4*)&Xs[row][col] =
                *(const float4*)&X[(size_t)(ph * 128 + row) * 64 + col];
        }
        __syncthreads();

        for (int gl = 0; gl < 32; gl += 4) {
#pragma unroll
            for (int j = 0; j < 4; ++j) {
                const int kloc = (gl + j) * 4;
                float2 xv0 = *(const float2*)&Xs[kloc + 0][tx * 2];
                float2 xv1 = *(const float2*)&Xs[kloc + 1][tx * 2];
                float2 xv2 = *(const float2*)&Xs[kloc + 2][tx * 2];
                float2 xv3 = *(const float2*)&Xs[kloc + 3][tx * 2];
#pragma unroll
                for (int i = 0; i < 4; ++i) {
                    acc[i][0] += bufs[j][i].x * xv0.x; acc[i][1] += bufs[j][i].x * xv0.y;
                    acc[i][0] += bufs[j][i].y * xv1.x; acc[i][1] += bufs[j][i].y * xv1.y;
                    acc[i][0] += bufs[j][i].z * xv2.x; acc[i][1] += bufs[j][i].z * xv2.y;
                    acc[i][0] += bufs[j][i].w * xv3.x; acc[i][1] += bufs[j][i].w * xv3.y;
                }
                int gnext = ph * 32 + gl + j + 4;   // global 4-k group to prefetch
                if (gnext < 128) {
#pragma unroll
                    for (int i = 0; i < 4; ++i)
                        bufs[j][i] = *(const float4*)(Arow + (size_t)i * 512 + gnext * 4);
                }
            }
        }
    }

    // epilogue: out[b][v], b = 2tx+jj, v = m0+4ty .. +3
#pragma unroll
    for (int jj = 0; jj < 2; ++jj) {
        int b = tx * 2 + jj;
        int v0 = m0 + ty * 4;
        float4 w;
        w.x = acc[0][jj] + bias[v0 + 0];
        w.y = acc[1][jj] + bias[v0 + 1];
        w.z = acc[2][jj] + bias[v0 + 2];
        w.w = acc[3][jj] + bias[v0 + 3];
        *(float4*)&outp[(size_t)b * V + v0] = w;
    }
}

// ---------------------------------------------------------------------------
extern "C" void kernel_launch(void* const* d_in, const int* in_sizes, int n_in,
                              void* d_out, int out_size, void* d_ws, size_t ws_size,
                              hipStream_t stream)
{
    const int*   x     = (const int*)d_in[0];
    const float* hdec  = (const float*)d_in[1];
    const float* enc   = (const float*)d_in[2];
    const float* h0    = (const float*)d_in[3];
    const float* c0    = (const float*)d_in[4];
    const float* emb   = (const float*)d_in[5];
    const float* w_ih1 = (const float*)d_in[6];
    const float* w_hh1 = (const float*)d_in[7];
    const float* b_ih1 = (const float*)d_in[8];
    const float* b_hh1 = (const float*)d_in[9];
    const float* w_ih  = (const float*)d_in[10];
    // d_in[11] = w_hh: multiplied by zero hidden state in layers 2-4 -> skipped
    const float* b_ih  = (const float*)d_in[12];
    const float* b_hh  = (const float*)d_in[13];
    const float* fc_w  = (const float*)d_in[14];
    const float* fc_b  = (const float*)d_in[15];

    float* out = (float*)d_out;
    float* ws  = (float*)d_ws;

    float* m_part   = ws;                                // 2048
    float* l_part   = ws + 2048;                         // 2048
    float* acc_part = ws + 4096;                         // 64*32*512
    float* inp_t    = acc_part + (size_t)B * NCHUNK * H; // 1280*64
    float* zA       = inp_t + 1280 * B;                  // 512*64
    float* zB       = zA + H * B;                        // 512*64

    float* out_h = out + (size_t)B * V;
    float* out_c = out_h + (size_t)B * H;

    // 1) attention (enc read once, 268 MB)
    attn_part_kernel<<<512, 256, 0, stream>>>(hdec, enc, m_part, l_part, acc_part);
    combine_kernel<<<64, 256, 0, stream>>>(m_part, l_part, acc_part, x, emb, h0, inp_t);

    // 2) LSTM layer 1: K = 768 (w_ih1) | 512 (w_hh1) = 1280, real c0
    lstm_fused_kernel<<<128, 256, 0, stream>>>(
        w_ih1, 768, 768, w_hh1, 512, 1280, inp_t,
        b_ih1, b_hh1, c0, zA, nullptr, nullptr);

    // 3) LSTM layers 2-4 (zero h/c: only w_ih contributes), K = 512
    lstm_fused_kernel<<<128, 256, 0, stream>>>(
        w_ih + 0 * (size_t)2048 * H, 512, 512, nullptr, 0, 512, zA,
        b_ih + 0 * 2048, b_hh + 0 * 2048, nullptr, zB, nullptr, nullptr);
    lstm_fused_kernel<<<128, 256, 0, stream>>>(
        w_ih + 1 * (size_t)2048 * H, 512, 512, nullptr, 0, 512, zB,
        b_ih + 1 * 2048, b_hh + 1 * 2048, nullptr, zA, nullptr, nullptr);
    lstm_fused_kernel<<<128, 256, 0, stream>>>(
        w_ih + 2 * (size_t)2048 * H, 512, 512, nullptr, 0, 512, zA,
        b_ih + 2 * 2048, b_hh + 2 * 2048, nullptr, zB, out_h, out_c);

    // 4) logits = zB^T @ fc_w^T + fc_b  (A global->reg once, X in 32KB LDS)
    fc_gemm_kernel<<<1000, 256, 0, stream>>>(fc_w, zB, out, fc_b);
}

// Round 9
// 1149.608 us; speedup vs baseline: 1.7484x; 1.7484x over previous
//
#include <hip/hip_runtime.h>
#include <cstdint>
#include <cstddef>

// Problem constants
constexpr int B = 64, S = 2048, H = 512, E = 256, V = 32000;
constexpr int NCHUNK = 32;   // attention: 32 chunks of 64 keys per batch

// ---------------------------------------------------------------------------
// Kernel 1: fused scores + online-softmax partials (enc read exactly once).
// One wave per (b, 64-key chunk); lane covers 8 of 512 dims (2 float4 slices).
// Software-pipelined key loop. Measured ~53 us vs 43 us HBM floor (ledger).
// ---------------------------------------------------------------------------
__global__ __launch_bounds__(256) void attn_part_kernel(
    const float* __restrict__ hd, const float* __restrict__ enc,
    float* __restrict__ m_part, float* __restrict__ l_part,
    float* __restrict__ acc_part)
{
    int b = blockIdx.x >> 3;
    int wave = threadIdx.x >> 6, lane = threadIdx.x & 63;
    int chunk = ((blockIdx.x & 7) << 2) + wave;
    int s0 = chunk * 64;

    const float4* hv = (const float4*)(hd + (size_t)b * H);
    float4 h0 = hv[lane], h1 = hv[64 + lane];
    const float4* ev = (const float4*)(enc + (size_t)b * S * H) + (size_t)s0 * (H / 4);

    float m = -1e30f, l = 0.f;
    float4 a0 = make_float4(0.f, 0.f, 0.f, 0.f);
    float4 a1 = make_float4(0.f, 0.f, 0.f, 0.f);
    float4 e0 = ev[lane], e1 = ev[64 + lane];

    auto process = [&](const float4& pe0, const float4& pe1) {
        float p = pe0.x * h0.x + pe0.y * h0.y + pe0.z * h0.z + pe0.w * h0.w
                + pe1.x * h1.x + pe1.y * h1.y + pe1.z * h1.z + pe1.w * h1.w;
#pragma unroll
        for (int off = 32; off; off >>= 1) p += __shfl_xor(p, off, 64);
        if (p <= m) {                 // wave-uniform branch
            float w = __expf(p - m);
            l += w;
            a0.x += w * pe0.x; a0.y += w * pe0.y; a0.z += w * pe0.z; a0.w += w * pe0.w;
            a1.x += w * pe1.x; a1.y += w * pe1.y; a1.z += w * pe1.z; a1.w += w * pe1.w;
        } else {
            float sc = __expf(m - p); // first iter: exp(-1e30)=0 -> exact init
            m = p;
            l = l * sc + 1.f;
            a0.x = a0.x * sc + pe0.x; a0.y = a0.y * sc + pe0.y;
            a0.z = a0.z * sc + pe0.z; a0.w = a0.w * sc + pe0.w;
            a1.x = a1.x * sc + pe1.x; a1.y = a1.y * sc + pe1.y;
            a1.z = a1.z * sc + pe1.z; a1.w = a1.w * sc + pe1.w;
        }
    };

    for (int s = 0; s < 63; ++s) {
        const float4* r = ev + (size_t)(s + 1) * (H / 4);
        float4 n0 = r[lane], n1 = r[64 + lane];   // prefetch next key
        process(e0, e1);                          // consume current key
        e0 = n0; e1 = n1;
    }
    process(e0, e1);                              // last key

    int base = b * NCHUNK + chunk;
    if (lane == 0) { m_part[base] = m; l_part[base] = l; }
    float4* ap = (float4*)(acc_part + (size_t)base * H);
    ap[lane] = a0; ap[64 + lane] = a1;
}

// ---------------------------------------------------------------------------
// Kernel 2: combine partials -> ctx; embedding gather; transposed LSTM input
// inp_t[k][b]: [0,256)=xe, [256,768)=ctx, [768,1280)=h0.  (~4 us in situ)
// ---------------------------------------------------------------------------
__global__ __launch_bounds__(256) void combine_kernel(
    const float* __restrict__ m_part, const float* __restrict__ l_part,
    const float* __restrict__ acc_part, const int* __restrict__ x,
    const float* __restrict__ emb, const float* __restrict__ h0,
    float* __restrict__ inp_t)
{
    int b = blockIdx.x, t = threadIdx.x;
    float M = -1e30f;
    for (int i = 0; i < NCHUNK; ++i) M = fmaxf(M, m_part[b * NCHUNK + i]);
    float L = 0.f;
    for (int i = 0; i < NCHUNK; ++i)
        L += l_part[b * NCHUNK + i] * __expf(m_part[b * NCHUNK + i] - M);
    float invL = 1.f / L;

    for (int d = t; d < H; d += 256) {
        float s = 0.f;
        for (int i = 0; i < NCHUNK; ++i)
            s += __expf(m_part[b * NCHUNK + i] - M) *
                 acc_part[((size_t)(b * NCHUNK + i)) * H + d];
        inp_t[(E + d) * B + b] = s * invL;
    }
    inp_t[t * B + b] = emb[(size_t)x[b] * E + t];
    for (int d = t; d < H; d += 256)
        inp_t[(E + H + d) * B + b] = h0[b * H + d];
}

// ---------------------------------------------------------------------------
// Kernel 3: fully-fused LSTM layer (round-5 proven version; ~5.5 us/layer).
// ---------------------------------------------------------------------------
__global__ __launch_bounds__(256) void lstm_fused_kernel(
    const float* __restrict__ A1, int lda1, int k1len,
    const float* __restrict__ A2, int lda2, int KT,
    const float* __restrict__ X,
    const float* __restrict__ b_ih, const float* __restrict__ b_hh,
    const float* __restrict__ c_prev,
    float* __restrict__ h_t, float* __restrict__ out_h, float* __restrict__ out_c)
{
    __shared__ float sm[4 * 32 * 20 + 4 * 32 * 64];   // As | Xs  (42.5 KB)
    float (*As)[32][20] = (float(*)[32][20])sm;
    float (*Xs)[32][64] = (float(*)[32][64])(sm + 4 * 32 * 20);
    float (*Ps)[16][64] = (float(*)[16][64])(sm + 4 * 32 * 20); // aliases Xs

    const int t = threadIdx.x;
    const int j0 = blockIdx.x * 4;
    const int QK = KT >> 2;
    const int nIter = QK >> 5;
    const int kq = t >> 6, r = t & 63, ty = r >> 4, tx = r & 15;

    float acc[4][4];
#pragma unroll
    for (int i = 0; i < 4; ++i)
#pragma unroll
        for (int j = 0; j < 4; ++j) acc[i][j] = 0.f;

    for (int it = 0; it < nIter; ++it) {
#pragma unroll
        for (int q = 0; q < 2; ++q) {
            int p = t + q * 256;
            int il = p >> 5, c = p & 31;
            int akq = c >> 3, k4 = (c & 7) * 4;
            int gk = akq * QK + it * 32 + k4;
            int grow = j0 + (il & 3) + 512 * (il >> 2);
            const float* src = (gk < k1len)
                ? A1 + (size_t)grow * lda1 + gk
                : A2 + (size_t)grow * lda2 + (gk - k1len);
            float4 v = *(const float4*)src;
            As[akq][k4 + 0][il] = v.x; As[akq][k4 + 1][il] = v.y;
            As[akq][k4 + 2][il] = v.z; As[akq][k4 + 3][il] = v.w;
        }
#pragma unroll
        for (int q = 0; q < 8; ++q) {
            int p = t + q * 256;
            int kk_all = p >> 4, col = (p & 15) * 4;
            int xkq = kk_all >> 5, kk = kk_all & 31;
            int gk = xkq * QK + it * 32 + kk;
            *(float4*)&Xs[xkq][kk][col] = *(const float4*)&X[(size_t)gk * 64 + col];
        }
        __syncthreads();

#pragma unroll 8
        for (int kk = 0; kk < 32; ++kk) {
            float4 av = *(const float4*)&As[kq][kk][ty * 4];
            float4 xv = *(const float4*)&Xs[kq][kk][tx * 4];
            float aa[4] = {av.x, av.y, av.z, av.w};
            float xx[4] = {xv.x, xv.y, xv.z, xv.w};
#pragma unroll
            for (int i = 0; i < 4; ++i)
#pragma unroll
                for (int j = 0; j < 4; ++j) acc[i][j] += aa[i] * xx[j];
        }
        __syncthreads();
    }

#pragma unroll
    for (int i = 0; i < 4; ++i)
        *(float4*)&Ps[kq][ty * 4 + i][tx * 4] =
            make_float4(acc[i][0], acc[i][1], acc[i][2], acc[i][3]);
    __syncthreads();

    for (int idx = t; idx < 16 * 64; idx += 256) {
        int row = idx >> 6, b = idx & 63;
        Ps[0][row][b] = Ps[0][row][b] + Ps[1][row][b] + Ps[2][row][b] + Ps[3][row][b];
    }
    __syncthreads();

    {
        int jj = t >> 6, b = t & 63;
        int j = j0 + jj;
        float gi = Ps[0][jj][b]      + b_ih[j]        + b_hh[j];
        float gf = Ps[0][4 + jj][b]  + b_ih[j + 512]  + b_hh[j + 512];
        float gg = Ps[0][8 + jj][b]  + b_ih[j + 1024] + b_hh[j + 1024];
        float go = Ps[0][12 + jj][b] + b_ih[j + 1536] + b_hh[j + 1536];
        float iv = 1.f / (1.f + __expf(-gi));
        float fv = 1.f / (1.f + __expf(-gf));
        float gv = tanhf(gg);
        float ov = 1.f / (1.f + __expf(-go));
        float cp = c_prev ? c_prev[b * H + j] : 0.f;
        float c2 = fv * cp + iv * gv;
        float hv = ov * tanhf(c2);
        h_t[j * B + b] = hv;
        if (out_h) { out_h[b * H + j] = hv; out_c[b * H + j] = c2; }
    }
}

// ---------------------------------------------------------------------------
// Kernel 4 (v5): fc logits = z^T @ fc_w^T + fc_b.
// A (fc_w): zero reuse -> streamed global->reg ONCE via 2-deep 16-k rotating
// buffers, fully static indexing (no copies, no spill: VGPR ~160 at
// 2 blocks/CU, cap 256). X in 64 KB LDS phase tiles.
// Thread map (SWAPPED vs v3/v4): tx = t&15 -> 4 vocab rows m0+4tx..+3
// (coalesced float4 output writes across the wave); ty = t>>4 -> 4 batch
// cols 4ty..+3 (only 4 unique Xs addresses per wave per k -> broadcast,
// conflict-free, LDS far below peak). 256 FMA / ~292 instr per buffer = 88%.
// ---------------------------------------------------------------------------
__global__ __launch_bounds__(256) void fc_gemm_kernel(
    const float* __restrict__ A, const float* __restrict__ X,
    float* __restrict__ outp, const float* __restrict__ bias)
{
    __shared__ float Xs[256][64];          // 64 KB phase tile of X

    const int t = threadIdx.x;
    const int tx = t & 15;                 // vocab rows m0 + 4*tx + i
    const int ty = t >> 4;                 // batch cols 4*(ty&3)... ty in 0..15
    const int by = ty & 3;                 // 4 batch cols: 4*by + j  (ty>=4 dup rows)
    const int m0 = blockIdx.x * 64;
    const int r0 = m0 + tx * 4 + (ty >> 2) * 0;   // tx picks 4 rows; ty>>2 unused for rows
    // NOTE: 16 tx-groups x 4 rows = 64 rows; ty in 0..15 -> (ty&3) batch group,
    // ty>>2 replicates across 4 sub-partitions of batch? No: we need 16 batch
    // groups. Correct map: 64 batch cols = 16 groups of 4 -> ty directly.
    (void)by; (void)r0;

    const int bg = ty;                     // batch group: cols 4*bg .. +3
    const float* Ab = A + (size_t)(m0 + tx * 4) * 512;

    float acc[4][4];                       // [i=row][j=col]
#pragma unroll
    for (int i = 0; i < 4; ++i)
#pragma unroll
        for (int j = 0; j < 4; ++j) acc[i][j] = 0.f;

    // 2-deep rotating A buffers: each holds 4 rows x 16 k = 16 float4.
    // bufX[i*4 + k4] = rows (m0+4tx+i), k = kbase + 4*k4 .. +3.
    float4 bufA[16], bufB[16];

#define LOADBUF(BUF, KB)                                                     \
    {                                                                        \
        const float* ap_ = Ab + (KB);                                        \
        _Pragma("unroll")                                                    \
        for (int i_ = 0; i_ < 4; ++i_)                                       \
            _Pragma("unroll")                                                \
            for (int k4_ = 0; k4_ < 4; ++k4_)                                \
                BUF[i_ * 4 + k4_] =                                          \
                    *(const float4*)(ap_ + (size_t)i_ * 512 + k4_ * 4);      \
    }

#define CONSUME(BUF, LK0)                                                    \
    {                                                                        \
        _Pragma("unroll")                                                    \
        for (int k4_ = 0; k4_ < 4; ++k4_) {                                  \
            _Pragma("unroll")                                                \
            for (int c_ = 0; c_ < 4; ++c_) {                                 \
                const int lk_ = (LK0) + k4_ * 4 + c_;                        \
                float4 xv_ = *(const float4*)&Xs[lk_][bg * 4];               \
                float a0_ = (c_ == 0) ? BUF[0 * 4 + k4_].x                   \
                          : (c_ == 1) ? BUF[0 * 4 + k4_].y                   \
                          : (c_ == 2) ? BUF[0 * 4 + k4_].z                   \
                                      : BUF[0 * 4 + k4_].w;                  \
                float a1_ = (c_ == 0) ? BUF[1 * 4 + k4_].x                   \
                          : (c_ == 1) ? BUF[1 * 4 + k4_].y                   \
                          : (c_ == 2) ? BUF[1 * 4 + k4_].z                   \
                                      : BUF[1 * 4 + k4_].w;                  \
                float a2_ = (c_ == 0) ? BUF[2 * 4 + k4_].x                   \
                          : (c_ == 1) ? BUF[2 * 4 + k4_].y                   \
                          : (c_ == 2) ? BUF[2 * 4 + k4_].z                   \
                                      : BUF[2 * 4 + k4_].w;                  \
                float a3_ = (c_ == 0) ? BUF[3 * 4 + k4_].x                   \
                          : (c_ == 1) ? BUF[3 * 4 + k4_].y                   \
                          : (c_ == 2) ? BUF[3 * 4 + k4_].z                   \
                                      : BUF[3 * 4 + k4_].w;                  \
                acc[0][0] += a0_ * xv_.x; acc[0][1] += a0_ * xv_.y;          \
                acc[0][2] += a0_ * xv_.z; acc[0][3] += a0_ * xv_.w;          \
                acc[1][0] += a1_ * xv_.x; acc[1][1] += a1_ * xv_.y;          \
                acc[1][2] += a1_ * xv_.z; acc[1][3] += a1_ * xv_.w;          \
                acc[2][0] += a2_ * xv_.x; acc[2][1] += a2_ * xv_.y;          \
                acc[2][2] += a2_ * xv_.z; acc[2][3] += a2_ * xv_.w;          \
                acc[3][0] += a3_ * xv_.x; acc[3][1] += a3_ * xv_.y;          \
                acc[3][2] += a3_ * xv_.z; acc[3][3] += a3_ * xv_.w;          \
            }                                                                \
        }                                                                    \
    }

    // prologue: fill both buffers (k 0..15, 16..31)
    LOADBUF(bufA, 0);
    LOADBUF(bufB, 16);
    int kn = 32;

    for (int ph = 0; ph < 2; ++ph) {
        __syncthreads();                   // all reads of prev Xs phase done
#pragma unroll
        for (int q = 0; q < 16; ++q) {     // stage 256 k x 64 b (16 f4/thread)
            int p = t + q * 256;
            int row = p >> 4, col = (p & 15) * 4;
            *(float4*)&Xs[row][col] =
                *(const float4*)&X[(size_t)(ph * 256 + row) * 64 + col];
        }
        __syncthreads();

        for (int it = 0; it < 8; ++it) {
            int lk0 = it * 32;
            CONSUME(bufA, lk0);
            if (kn < 512) LOADBUF(bufA, kn);
            kn += 16;
            CONSUME(bufB, lk0 + 16);
            if (kn < 512) LOADBUF(bufB, kn);
            kn += 16;
        }
    }
#undef LOADBUF
#undef CONSUME

    // epilogue: out[b][v], b = 4*bg+j, v = m0+4*tx .. +3 (coalesced over tx)
#pragma unroll
    for (int j = 0; j < 4; ++j) {
        int b = bg * 4 + j;
        int v0 = m0 + tx * 4;
        float4 w;
        w.x = acc[0][j] + bias[v0 + 0];
        w.y = acc[1][j] + bias[v0 + 1];
        w.z = acc[2][j] + bias[v0 + 2];
        w.w = acc[3][j] + bias[v0 + 3];
        *(float4*)&outp[(size_t)b * V + v0] = w;
    }
}

// ---------------------------------------------------------------------------
extern "C" void kernel_launch(void* const* d_in, const int* in_sizes, int n_in,
                              void* d_out, int out_size, void* d_ws, size_t ws_size,
                              hipStream_t stream)
{
    const int*   x     = (const int*)d_in[0];
    const float* hdec  = (const float*)d_in[1];
    const float* enc   = (const float*)d_in[2];
    const float* h0    = (const float*)d_in[3];
    const float* c0    = (const float*)d_in[4];
    const float* emb   = (const float*)d_in[5];
    const float* w_ih1 = (const float*)d_in[6];
    const float* w_hh1 = (const float*)d_in[7];
    const float* b_ih1 = (const float*)d_in[8];
    const float* b_hh1 = (const float*)d_in[9];
    const float* w_ih  = (const float*)d_in[10];
    // d_in[11] = w_hh: multiplied by zero hidden state in layers 2-4 -> skipped
    const float* b_ih  = (const float*)d_in[12];
    const float* b_hh  = (const float*)d_in[13];
    const float* fc_w  = (const float*)d_in[14];
    const float* fc_b  = (const float*)d_in[15];

    float* out = (float*)d_out;
    float* ws  = (float*)d_ws;

    float* m_part   = ws;                                // 2048
    float* l_part   = ws + 2048;                         // 2048
    float* acc_part = ws + 4096;                         // 64*32*512
    float* inp_t    = acc_part + (size_t)B * NCHUNK * H; // 1280*64
    float* zA       = inp_t + 1280 * B;                  // 512*64
    float* zB       = zA + H * B;                        // 512*64

    float* out_h = out + (size_t)B * V;
    float* out_c = out_h + (size_t)B * H;

    // 1) attention (enc read once, 268 MB)
    attn_part_kernel<<<512, 256, 0, stream>>>(hdec, enc, m_part, l_part, acc_part);
    combine_kernel<<<64, 256, 0, stream>>>(m_part, l_part, acc_part, x, emb, h0, inp_t);

    // 2) LSTM layer 1: K = 768 (w_ih1) | 512 (w_hh1) = 1280, real c0
    lstm_fused_kernel<<<128, 256, 0, stream>>>(
        w_ih1, 768, 768, w_hh1, 512, 1280, inp_t,
        b_ih1, b_hh1, c0, zA, nullptr, nullptr);

    // 3) LSTM layers 2-4 (zero h/c: only w_ih contributes), K = 512
    lstm_fused_kernel<<<128, 256, 0, stream>>>(
        w_ih + 0 * (size_t)2048 * H, 512, 512, nullptr, 0, 512, zA,
        b_ih + 0 * 2048, b_hh + 0 * 2048, nullptr, zB, nullptr, nullptr);
    lstm_fused_kernel<<<128, 256, 0, stream>>>(
        w_ih + 1 * (size_t)2048 * H, 512, 512, nullptr, 0, 512, zB,
        b_ih + 1 * 2048, b_hh + 1 * 2048, nullptr, zA, nullptr, nullptr);
    lstm_fused_kernel<<<128, 256, 0, stream>>>(
        w_ih + 2 * (size_t)2048 * H, 512, 512, nullptr, 0, 512, zA,
        b_ih + 2 * 2048, b_hh + 2 * 2048, nullptr, zB, out_h, out_c);

    // 4) logits = zB^T @ fc_w^T + fc_b  (A global->reg once, X in 64KB LDS)
    fc_gemm_kernel<<<500, 256, 0, stream>>>(fc_w, zB, out, fc_b);
}

// Round 10
// 181.387 us; speedup vs baseline: 11.0812x; 6.3379x over previous
//
#include <hip/hip_runtime.h>
#include <cstdint>
#include <cstddef>

// Problem constants
constexpr int B = 64, S = 2048, H = 512, E = 256, V = 32000;
constexpr int NCHUNK = 32;   // attention: 32 chunks of 64 keys per batch

// ---------------------------------------------------------------------------
// Kernel 1: fused scores + online-softmax partials (enc read exactly once).
// One wave per (b, 64-key chunk); lane covers 8 of 512 dims (2 float4 slices).
// Software-pipelined key loop. Measured ~53 us vs 43 us HBM floor (ledger).
// ---------------------------------------------------------------------------
__global__ __launch_bounds__(256) void attn_part_kernel(
    const float* __restrict__ hd, const float* __restrict__ enc,
    float* __restrict__ m_part, float* __restrict__ l_part,
    float* __restrict__ acc_part)
{
    int b = blockIdx.x >> 3;
    int wave = threadIdx.x >> 6, lane = threadIdx.x & 63;
    int chunk = ((blockIdx.x & 7) << 2) + wave;
    int s0 = chunk * 64;

    const float4* hv = (const float4*)(hd + (size_t)b * H);
    float4 h0 = hv[lane], h1 = hv[64 + lane];
    const float4* ev = (const float4*)(enc + (size_t)b * S * H) + (size_t)s0 * (H / 4);

    float m = -1e30f, l = 0.f;
    float4 a0 = make_float4(0.f, 0.f, 0.f, 0.f);
    float4 a1 = make_float4(0.f, 0.f, 0.f, 0.f);
    float4 e0 = ev[lane], e1 = ev[64 + lane];

    auto process = [&](const float4& pe0, const float4& pe1) {
        float p = pe0.x * h0.x + pe0.y * h0.y + pe0.z * h0.z + pe0.w * h0.w
                + pe1.x * h1.x + pe1.y * h1.y + pe1.z * h1.z + pe1.w * h1.w;
#pragma unroll
        for (int off = 32; off; off >>= 1) p += __shfl_xor(p, off, 64);
        if (p <= m) {                 // wave-uniform branch
            float w = __expf(p - m);
            l += w;
            a0.x += w * pe0.x; a0.y += w * pe0.y; a0.z += w * pe0.z; a0.w += w * pe0.w;
            a1.x += w * pe1.x; a1.y += w * pe1.y; a1.z += w * pe1.z; a1.w += w * pe1.w;
        } else {
            float sc = __expf(m - p); // first iter: exp(-1e30)=0 -> exact init
            m = p;
            l = l * sc + 1.f;
            a0.x = a0.x * sc + pe0.x; a0.y = a0.y * sc + pe0.y;
            a0.z = a0.z * sc + pe0.z; a0.w = a0.w * sc + pe0.w;
            a1.x = a1.x * sc + pe1.x; a1.y = a1.y * sc + pe1.y;
            a1.z = a1.z * sc + pe1.z; a1.w = a1.w * sc + pe1.w;
        }
    };

    for (int s = 0; s < 63; ++s) {
        const float4* r = ev + (size_t)(s + 1) * (H / 4);
        float4 n0 = r[lane], n1 = r[64 + lane];   // prefetch next key
        process(e0, e1);                          // consume current key
        e0 = n0; e1 = n1;
    }
    process(e0, e1);                              // last key

    int base = b * NCHUNK + chunk;
    if (lane == 0) { m_part[base] = m; l_part[base] = l; }
    float4* ap = (float4*)(acc_part + (size_t)base * H);
    ap[lane] = a0; ap[64 + lane] = a1;
}

// ---------------------------------------------------------------------------
// Kernel 2: combine partials -> ctx; embedding gather; transposed LSTM input
// inp_t[k][b]: [0,256)=xe, [256,768)=ctx, [768,1280)=h0.  (~4 us in situ)
// ---------------------------------------------------------------------------
__global__ __launch_bounds__(256) void combine_kernel(
    const float* __restrict__ m_part, const float* __restrict__ l_part,
    const float* __restrict__ acc_part, const int* __restrict__ x,
    const float* __restrict__ emb, const float* __restrict__ h0,
    float* __restrict__ inp_t)
{
    int b = blockIdx.x, t = threadIdx.x;
    float M = -1e30f;
    for (int i = 0; i < NCHUNK; ++i) M = fmaxf(M, m_part[b * NCHUNK + i]);
    float L = 0.f;
    for (int i = 0; i < NCHUNK; ++i)
        L += l_part[b * NCHUNK + i] * __expf(m_part[b * NCHUNK + i] - M);
    float invL = 1.f / L;

    for (int d = t; d < H; d += 256) {
        float s = 0.f;
        for (int i = 0; i < NCHUNK; ++i)
            s += __expf(m_part[b * NCHUNK + i] - M) *
                 acc_part[((size_t)(b * NCHUNK + i)) * H + d];
        inp_t[(E + d) * B + b] = s * invL;
    }
    inp_t[t * B + b] = emb[(size_t)x[b] * E + t];
    for (int d = t; d < H; d += 256)
        inp_t[(E + H + d) * B + b] = h0[b * H + d];
}

// ---------------------------------------------------------------------------
// Kernel 3: fully-fused LSTM layer (round-5 proven version; ~5.5 us/layer).
// ---------------------------------------------------------------------------
__global__ __launch_bounds__(256) void lstm_fused_kernel(
    const float* __restrict__ A1, int lda1, int k1len,
    const float* __restrict__ A2, int lda2, int KT,
    const float* __restrict__ X,
    const float* __restrict__ b_ih, const float* __restrict__ b_hh,
    const float* __restrict__ c_prev,
    float* __restrict__ h_t, float* __restrict__ out_h, float* __restrict__ out_c)
{
    __shared__ float sm[4 * 32 * 20 + 4 * 32 * 64];   // As | Xs  (42.5 KB)
    float (*As)[32][20] = (float(*)[32][20])sm;
    float (*Xs)[32][64] = (float(*)[32][64])(sm + 4 * 32 * 20);
    float (*Ps)[16][64] = (float(*)[16][64])(sm + 4 * 32 * 20); // aliases Xs

    const int t = threadIdx.x;
    const int j0 = blockIdx.x * 4;
    const int QK = KT >> 2;
    const int nIter = QK >> 5;
    const int kq = t >> 6, r = t & 63, ty = r >> 4, tx = r & 15;

    float acc[4][4];
#pragma unroll
    for (int i = 0; i < 4; ++i)
#pragma unroll
        for (int j = 0; j < 4; ++j) acc[i][j] = 0.f;

    for (int it = 0; it < nIter; ++it) {
#pragma unroll
        for (int q = 0; q < 2; ++q) {
            int p = t + q * 256;
            int il = p >> 5, c = p & 31;
            int akq = c >> 3, k4 = (c & 7) * 4;
            int gk = akq * QK + it * 32 + k4;
            int grow = j0 + (il & 3) + 512 * (il >> 2);
            const float* src = (gk < k1len)
                ? A1 + (size_t)grow * lda1 + gk
                : A2 + (size_t)grow * lda2 + (gk - k1len);
            float4 v = *(const float4*)src;
            As[akq][k4 + 0][il] = v.x; As[akq][k4 + 1][il] = v.y;
            As[akq][k4 + 2][il] = v.z; As[akq][k4 + 3][il] = v.w;
        }
#pragma unroll
        for (int q = 0; q < 8; ++q) {
            int p = t + q * 256;
            int kk_all = p >> 4, col = (p & 15) * 4;
            int xkq = kk_all >> 5, kk = kk_all & 31;
            int gk = xkq * QK + it * 32 + kk;
            *(float4*)&Xs[xkq][kk][col] = *(const float4*)&X[(size_t)gk * 64 + col];
        }
        __syncthreads();

#pragma unroll 8
        for (int kk = 0; kk < 32; ++kk) {
            float4 av = *(const float4*)&As[kq][kk][ty * 4];
            float4 xv = *(const float4*)&Xs[kq][kk][tx * 4];
            float aa[4] = {av.x, av.y, av.z, av.w};
            float xx[4] = {xv.x, xv.y, xv.z, xv.w};
#pragma unroll
            for (int i = 0; i < 4; ++i)
#pragma unroll
                for (int j = 0; j < 4; ++j) acc[i][j] += aa[i] * xx[j];
        }
        __syncthreads();
    }

#pragma unroll
    for (int i = 0; i < 4; ++i)
        *(float4*)&Ps[kq][ty * 4 + i][tx * 4] =
            make_float4(acc[i][0], acc[i][1], acc[i][2], acc[i][3]);
    __syncthreads();

    for (int idx = t; idx < 16 * 64; idx += 256) {
        int row = idx >> 6, b = idx & 63;
        Ps[0][row][b] = Ps[0][row][b] + Ps[1][row][b] + Ps[2][row][b] + Ps[3][row][b];
    }
    __syncthreads();

    {
        int jj = t >> 6, b = t & 63;
        int j = j0 + jj;
        float gi = Ps[0][jj][b]      + b_ih[j]        + b_hh[j];
        float gf = Ps[0][4 + jj][b]  + b_ih[j + 512]  + b_hh[j + 512];
        float gg = Ps[0][8 + jj][b]  + b_ih[j + 1024] + b_hh[j + 1024];
        float go = Ps[0][12 + jj][b] + b_ih[j + 1536] + b_hh[j + 1536];
        float iv = 1.f / (1.f + __expf(-gi));
        float fv = 1.f / (1.f + __expf(-gf));
        float gv = tanhf(gg);
        float ov = 1.f / (1.f + __expf(-go));
        float cp = c_prev ? c_prev[b * H + j] : 0.f;
        float c2 = fv * cp + iv * gv;
        float hv = ov * tanhf(c2);
        h_t[j * B + b] = hv;
        if (out_h) { out_h[b * H + j] = hv; out_c[b * H + j] = c2; }
    }
}

// ---------------------------------------------------------------------------
// Kernel 4 (v6): fc logits = z^T @ fc_w^T + fc_b.
// Classic tiled GEMM, both operands via LDS (register-prefetch designs spilled
// twice — v4: 64-VGPR cap, v5: 256-VGPR + 2.7 GB scratch; LDS-staged frags are
// the safe design). BM=128, BN=64, BK=32, 256 thr, micro 4x8: acc=32 VGPR,
// frags=12 -> ~90-110 VGPR, no spill. A tile transposed [32][132] (pad 4 ->
// <=2-way on b128 reads, free). A global loads: 8 lanes x 128 B contiguous,
// read exactly once (64 MB). Per k-step: 3 ds_read_b128 + 32 FMA (84% FMA).
// 250 blocks. FLOP floor 13.4 us -> expect ~16-20 us.
// ---------------------------------------------------------------------------
__global__ __launch_bounds__(256) void fc_gemm_kernel(
    const float* __restrict__ A, const float* __restrict__ X,
    float* __restrict__ outp, const float* __restrict__ bias)
{
    __shared__ float As[32][132];   // [k][row], +4 pad
    __shared__ float Xs[32][64];

    const int t = threadIdx.x;
    const int tx = t & 7;           // col group: cols 8*tx .. +7
    const int ty = t >> 3;          // row group: rows m0 + 4*ty .. +3  (ty<32)
    const int m0 = blockIdx.x * 128;

    float acc[4][8];
#pragma unroll
    for (int i = 0; i < 4; ++i)
#pragma unroll
        for (int j = 0; j < 8; ++j) acc[i][j] = 0.f;

    for (int k0 = 0; k0 < 512; k0 += 32) {
        // stage A tile: 128 rows x 32 k, transposed. 4 float4/thread.
        // lanes 0..7 cover one row's 128 B contiguous -> coalesced.
#pragma unroll
        for (int q = 0; q < 4; ++q) {
            int row = (t >> 3) + q * 32;
            int k4 = (t & 7) * 4;
            float4 v = *(const float4*)&A[(size_t)(m0 + row) * 512 + k0 + k4];
            As[k4 + 0][row] = v.x; As[k4 + 1][row] = v.y;
            As[k4 + 2][row] = v.z; As[k4 + 3][row] = v.w;
        }
        // stage X tile: 32 k x 64 cols. 2 float4/thread.
#pragma unroll
        for (int q = 0; q < 2; ++q) {
            int p = t + q * 256;
            int row = p >> 4, col = (p & 15) * 4;
            *(float4*)&Xs[row][col] =
                *(const float4*)&X[(size_t)(k0 + row) * 64 + col];
        }
        __syncthreads();

#pragma unroll 8
        for (int k = 0; k < 32; ++k) {
            float4 av  = *(const float4*)&As[k][ty * 4];
            float4 xv0 = *(const float4*)&Xs[k][tx * 8];
            float4 xv1 = *(const float4*)&Xs[k][tx * 8 + 4];
            float aa[4] = {av.x, av.y, av.z, av.w};
            float xx[8] = {xv0.x, xv0.y, xv0.z, xv0.w,
                           xv1.x, xv1.y, xv1.z, xv1.w};
#pragma unroll
            for (int i = 0; i < 4; ++i)
#pragma unroll
                for (int j = 0; j < 8; ++j)
                    acc[i][j] += aa[i] * xx[j];
        }
        __syncthreads();
    }

    // epilogue: out[b][v], b = 8*tx+j, v = m0+4*ty .. +3 (float4, coalesced
    // across ty groups within each column j)
#pragma unroll
    for (int j = 0; j < 8; ++j) {
        int b = tx * 8 + j;
        int v0 = m0 + ty * 4;
        float4 w;
        w.x = acc[0][j] + bias[v0 + 0];
        w.y = acc[1][j] + bias[v0 + 1];
        w.z = acc[2][j] + bias[v0 + 2];
        w.w = acc[3][j] + bias[v0 + 3];
        *(float4*)&outp[(size_t)b * V + v0] = w;
    }
}

// ---------------------------------------------------------------------------
extern "C" void kernel_launch(void* const* d_in, const int* in_sizes, int n_in,
                              void* d_out, int out_size, void* d_ws, size_t ws_size,
                              hipStream_t stream)
{
    const int*   x     = (const int*)d_in[0];
    const float* hdec  = (const float*)d_in[1];
    const float* enc   = (const float*)d_in[2];
    const float* h0    = (const float*)d_in[3];
    const float* c0    = (const float*)d_in[4];
    const float* emb   = (const float*)d_in[5];
    const float* w_ih1 = (const float*)d_in[6];
    const float* w_hh1 = (const float*)d_in[7];
    const float* b_ih1 = (const float*)d_in[8];
    const float* b_hh1 = (const float*)d_in[9];
    const float* w_ih  = (const float*)d_in[10];
    // d_in[11] = w_hh: multiplied by zero hidden state in layers 2-4 -> skipped
    const float* b_ih  = (const float*)d_in[12];
    const float* b_hh  = (const float*)d_in[13];
    const float* fc_w  = (const float*)d_in[14];
    const float* fc_b  = (const float*)d_in[15];

    float* out = (float*)d_out;
    float* ws  = (float*)d_ws;

    float* m_part   = ws;                                // 2048
    float* l_part   = ws + 2048;                         // 2048
    float* acc_part = ws + 4096;                         // 64*32*512
    float* inp_t    = acc_part + (size_t)B * NCHUNK * H; // 1280*64
    float* zA       = inp_t + 1280 * B;                  // 512*64
    float* zB       = zA + H * B;                        // 512*64

    float* out_h = out + (size_t)B * V;
    float* out_c = out_h + (size_t)B * H;

    // 1) attention (enc read once, 268 MB)
    attn_part_kernel<<<512, 256, 0, stream>>>(hdec, enc, m_part, l_part, acc_part);
    combine_kernel<<<64, 256, 0, stream>>>(m_part, l_part, acc_part, x, emb, h0, inp_t);

    // 2) LSTM layer 1: K = 768 (w_ih1) | 512 (w_hh1) = 1280, real c0
    lstm_fused_kernel<<<128, 256, 0, stream>>>(
        w_ih1, 768, 768, w_hh1, 512, 1280, inp_t,
        b_ih1, b_hh1, c0, zA, nullptr, nullptr);

    // 3) LSTM layers 2-4 (zero h/c: only w_ih contributes), K = 512
    lstm_fused_kernel<<<128, 256, 0, stream>>>(
        w_ih + 0 * (size_t)2048 * H, 512, 512, nullptr, 0, 512, zA,
        b_ih + 0 * 2048, b_hh + 0 * 2048, nullptr, zB, nullptr, nullptr);
    lstm_fused_kernel<<<128, 256, 0, stream>>>(
        w_ih + 1 * (size_t)2048 * H, 512, 512, nullptr, 0, 512, zB,
        b_ih + 1 * 2048, b_hh + 1 * 2048, nullptr, zA, nullptr, nullptr);
    lstm_fused_kernel<<<128, 256, 0, stream>>>(
        w_ih + 2 * (size_t)2048 * H, 512, 512, nullptr, 0, 512, zA,
        b_ih + 2 * 2048, b_hh + 2 * 2048, nullptr, zB, out_h, out_c);

    // 4) logits = zB^T @ fc_w^T + fc_b  (classic LDS-tiled GEMM)
    fc_gemm_kernel<<<250, 256, 0, stream>>>(fc_w, zB, out, fc_b);
}

// Round 11
// 171.271 us; speedup vs baseline: 11.7357x; 1.0591x over previous
//
#include <hip/hip_runtime.h>
#include <cstdint>
#include <cstddef>

// Problem constants
constexpr int B = 64, S = 2048, H = 512, E = 256, V = 32000;
constexpr int NCHUNK = 32;   // attention: 32 chunks of 64 keys per batch

// ---------------------------------------------------------------------------
// Kernel 1: fused scores + online-softmax partials (enc read exactly once).
// One wave per (b, 64-key chunk); lane covers 8 of 512 dims (2 float4 slices).
// Software-pipelined key loop. Measured ~54 us vs 43 us HBM floor (ledger).
// ---------------------------------------------------------------------------
__global__ __launch_bounds__(256) void attn_part_kernel(
    const float* __restrict__ hd, const float* __restrict__ enc,
    float* __restrict__ m_part, float* __restrict__ l_part,
    float* __restrict__ acc_part)
{
    int b = blockIdx.x >> 3;
    int wave = threadIdx.x >> 6, lane = threadIdx.x & 63;
    int chunk = ((blockIdx.x & 7) << 2) + wave;
    int s0 = chunk * 64;

    const float4* hv = (const float4*)(hd + (size_t)b * H);
    float4 h0 = hv[lane], h1 = hv[64 + lane];
    const float4* ev = (const float4*)(enc + (size_t)b * S * H) + (size_t)s0 * (H / 4);

    float m = -1e30f, l = 0.f;
    float4 a0 = make_float4(0.f, 0.f, 0.f, 0.f);
    float4 a1 = make_float4(0.f, 0.f, 0.f, 0.f);
    float4 e0 = ev[lane], e1 = ev[64 + lane];

    auto process = [&](const float4& pe0, const float4& pe1) {
        float p = pe0.x * h0.x + pe0.y * h0.y + pe0.z * h0.z + pe0.w * h0.w
                + pe1.x * h1.x + pe1.y * h1.y + pe1.z * h1.z + pe1.w * h1.w;
#pragma unroll
        for (int off = 32; off; off >>= 1) p += __shfl_xor(p, off, 64);
        if (p <= m) {                 // wave-uniform branch
            float w = __expf(p - m);
            l += w;
            a0.x += w * pe0.x; a0.y += w * pe0.y; a0.z += w * pe0.z; a0.w += w * pe0.w;
            a1.x += w * pe1.x; a1.y += w * pe1.y; a1.z += w * pe1.z; a1.w += w * pe1.w;
        } else {
            float sc = __expf(m - p); // first iter: exp(-1e30)=0 -> exact init
            m = p;
            l = l * sc + 1.f;
            a0.x = a0.x * sc + pe0.x; a0.y = a0.y * sc + pe0.y;
            a0.z = a0.z * sc + pe0.z; a0.w = a0.w * sc + pe0.w;
            a1.x = a1.x * sc + pe1.x; a1.y = a1.y * sc + pe1.y;
            a1.z = a1.z * sc + pe1.z; a1.w = a1.w * sc + pe1.w;
        }
    };

    for (int s = 0; s < 63; ++s) {
        const float4* r = ev + (size_t)(s + 1) * (H / 4);
        float4 n0 = r[lane], n1 = r[64 + lane];   // prefetch next key
        process(e0, e1);                          // consume current key
        e0 = n0; e1 = n1;
    }
    process(e0, e1);                              // last key

    int base = b * NCHUNK + chunk;
    if (lane == 0) { m_part[base] = m; l_part[base] = l; }
    float4* ap = (float4*)(acc_part + (size_t)base * H);
    ap[lane] = a0; ap[64 + lane] = a1;
}

// ---------------------------------------------------------------------------
// Kernel 2: combine partials -> ctx; embedding gather; transposed LSTM input
// inp_t[k][b]: [0,256)=xe, [256,768)=ctx, [768,1280)=h0.  (~4 us in situ)
// ---------------------------------------------------------------------------
__global__ __launch_bounds__(256) void combine_kernel(
    const float* __restrict__ m_part, const float* __restrict__ l_part,
    const float* __restrict__ acc_part, const int* __restrict__ x,
    const float* __restrict__ emb, const float* __restrict__ h0,
    float* __restrict__ inp_t)
{
    int b = blockIdx.x, t = threadIdx.x;
    float M = -1e30f;
    for (int i = 0; i < NCHUNK; ++i) M = fmaxf(M, m_part[b * NCHUNK + i]);
    float L = 0.f;
    for (int i = 0; i < NCHUNK; ++i)
        L += l_part[b * NCHUNK + i] * __expf(m_part[b * NCHUNK + i] - M);
    float invL = 1.f / L;

    for (int d = t; d < H; d += 256) {
        float s = 0.f;
        for (int i = 0; i < NCHUNK; ++i)
            s += __expf(m_part[b * NCHUNK + i] - M) *
                 acc_part[((size_t)(b * NCHUNK + i)) * H + d];
        inp_t[(E + d) * B + b] = s * invL;
    }
    inp_t[t * B + b] = emb[(size_t)x[b] * E + t];
    for (int d = t; d < H; d += 256)
        inp_t[(E + H + d) * B + b] = h0[b * H + d];
}

// ---------------------------------------------------------------------------
// Kernel 3: fully-fused LSTM layer (round-5 proven version; ~5.5 us/layer).
// ---------------------------------------------------------------------------
__global__ __launch_bounds__(256) void lstm_fused_kernel(
    const float* __restrict__ A1, int lda1, int k1len,
    const float* __restrict__ A2, int lda2, int KT,
    const float* __restrict__ X,
    const float* __restrict__ b_ih, const float* __restrict__ b_hh,
    const float* __restrict__ c_prev,
    float* __restrict__ h_t, float* __restrict__ out_h, float* __restrict__ out_c)
{
    __shared__ float sm[4 * 32 * 20 + 4 * 32 * 64];   // As | Xs  (42.5 KB)
    float (*As)[32][20] = (float(*)[32][20])sm;
    float (*Xs)[32][64] = (float(*)[32][64])(sm + 4 * 32 * 20);
    float (*Ps)[16][64] = (float(*)[16][64])(sm + 4 * 32 * 20); // aliases Xs

    const int t = threadIdx.x;
    const int j0 = blockIdx.x * 4;
    const int QK = KT >> 2;
    const int nIter = QK >> 5;
    const int kq = t >> 6, r = t & 63, ty = r >> 4, tx = r & 15;

    float acc[4][4];
#pragma unroll
    for (int i = 0; i < 4; ++i)
#pragma unroll
        for (int j = 0; j < 4; ++j) acc[i][j] = 0.f;

    for (int it = 0; it < nIter; ++it) {
#pragma unroll
        for (int q = 0; q < 2; ++q) {
            int p = t + q * 256;
            int il = p >> 5, c = p & 31;
            int akq = c >> 3, k4 = (c & 7) * 4;
            int gk = akq * QK + it * 32 + k4;
            int grow = j0 + (il & 3) + 512 * (il >> 2);
            const float* src = (gk < k1len)
                ? A1 + (size_t)grow * lda1 + gk
                : A2 + (size_t)grow * lda2 + (gk - k1len);
            float4 v = *(const float4*)src;
            As[akq][k4 + 0][il] = v.x; As[akq][k4 + 1][il] = v.y;
            As[akq][k4 + 2][il] = v.z; As[akq][k4 + 3][il] = v.w;
        }
#pragma unroll
        for (int q = 0; q < 8; ++q) {
            int p = t + q * 256;
            int kk_all = p >> 4, col = (p & 15) * 4;
            int xkq = kk_all >> 5, kk = kk_all & 31;
            int gk = xkq * QK + it * 32 + kk;
            *(float4*)&Xs[xkq][kk][col] = *(const float4*)&X[(size_t)gk * 64 + col];
        }
        __syncthreads();

#pragma unroll 8
        for (int kk = 0; kk < 32; ++kk) {
            float4 av = *(const float4*)&As[kq][kk][ty * 4];
            float4 xv = *(const float4*)&Xs[kq][kk][tx * 4];
            float aa[4] = {av.x, av.y, av.z, av.w};
            float xx[4] = {xv.x, xv.y, xv.z, xv.w};
#pragma unroll
            for (int i = 0; i < 4; ++i)
#pragma unroll
                for (int j = 0; j < 4; ++j) acc[i][j] += aa[i] * xx[j];
        }
        __syncthreads();
    }

#pragma unroll
    for (int i = 0; i < 4; ++i)
        *(float4*)&Ps[kq][ty * 4 + i][tx * 4] =
            make_float4(acc[i][0], acc[i][1], acc[i][2], acc[i][3]);
    __syncthreads();

    for (int idx = t; idx < 16 * 64; idx += 256) {
        int row = idx >> 6, b = idx & 63;
        Ps[0][row][b] = Ps[0][row][b] + Ps[1][row][b] + Ps[2][row][b] + Ps[3][row][b];
    }
    __syncthreads();

    {
        int jj = t >> 6, b = t & 63;
        int j = j0 + jj;
        float gi = Ps[0][jj][b]      + b_ih[j]        + b_hh[j];
        float gf = Ps[0][4 + jj][b]  + b_ih[j + 512]  + b_hh[j + 512];
        float gg = Ps[0][8 + jj][b]  + b_ih[j + 1024] + b_hh[j + 1024];
        float go = Ps[0][12 + jj][b] + b_ih[j + 1536] + b_hh[j + 1536];
        float iv = 1.f / (1.f + __expf(-gi));
        float fv = 1.f / (1.f + __expf(-gf));
        float gv = tanhf(gg);
        float ov = 1.f / (1.f + __expf(-go));
        float cp = c_prev ? c_prev[b * H + j] : 0.f;
        float c2 = fv * cp + iv * gv;
        float hv = ov * tanhf(c2);
        h_t[j * B + b] = hv;
        if (out_h) { out_h[b * H + j] = hv; out_c[b * H + j] = c2; }
    }
}

// ---------------------------------------------------------------------------
// Kernel 4 (v7): fc logits = z^T @ fc_w^T + fc_b.
// v6 retro: correct structure but grid=250 -> 1 block/CU -> 1 wave/SIMD ->
// LDS latency fully exposed (~63 us). v7: BM=64, micro 4x4 (acc 16 + frags 8
// -> ~75 VGPR), grid=500 -> 2+ blocks/CU, LDS 17 KB -> HW can pack up to 4
// -> 8-16 waves/CU for latency hiding. Same staging pattern (proven, 0
// conflicts): A transposed [32][68] pad 4; per-wave reads broadcast-friendly.
// ---------------------------------------------------------------------------
__global__ __launch_bounds__(256) void fc_gemm_kernel(
    const float* __restrict__ A, const float* __restrict__ X,
    float* __restrict__ outp, const float* __restrict__ bias)
{
    __shared__ float As[32][68];    // [k][row], +4 pad  (8.7 KB)
    __shared__ float Xs[32][64];    // (8 KB)

    const int t = threadIdx.x;
    const int tx = t & 15;          // col group: cols 4*tx .. +3
    const int ty = t >> 4;          // row group: rows m0 + 4*ty .. +3 (ty<16)
    const int m0 = blockIdx.x * 64;

    float acc[4][4];
#pragma unroll
    for (int i = 0; i < 4; ++i)
#pragma unroll
        for (int j = 0; j < 4; ++j) acc[i][j] = 0.f;

    for (int k0 = 0; k0 < 512; k0 += 32) {
        // stage A tile: 64 rows x 32 k, transposed. 2 float4/thread.
        // lanes 0..7 cover one row's 128 B contiguous -> coalesced.
#pragma unroll
        for (int q = 0; q < 2; ++q) {
            int row = (t >> 3) + q * 32;
            int k4 = (t & 7) * 4;
            float4 v = *(const float4*)&A[(size_t)(m0 + row) * 512 + k0 + k4];
            As[k4 + 0][row] = v.x; As[k4 + 1][row] = v.y;
            As[k4 + 2][row] = v.z; As[k4 + 3][row] = v.w;
        }
        // stage X tile: 32 k x 64 cols. 2 float4/thread.
#pragma unroll
        for (int q = 0; q < 2; ++q) {
            int p = t + q * 256;
            int row = p >> 4, col = (p & 15) * 4;
            *(float4*)&Xs[row][col] =
                *(const float4*)&X[(size_t)(k0 + row) * 64 + col];
        }
        __syncthreads();

#pragma unroll 8
        for (int k = 0; k < 32; ++k) {
            float4 av = *(const float4*)&As[k][ty * 4];
            float4 xv = *(const float4*)&Xs[k][tx * 4];
            float aa[4] = {av.x, av.y, av.z, av.w};
            float xx[4] = {xv.x, xv.y, xv.z, xv.w};
#pragma unroll
            for (int i = 0; i < 4; ++i)
#pragma unroll
                for (int j = 0; j < 4; ++j)
                    acc[i][j] += aa[i] * xx[j];
        }
        __syncthreads();
    }

    // epilogue: out[b][v], b = 4*tx+j, v = m0+4*ty .. +3; lanes sharing b
    // (4 ty values) write 64 B contiguous.
#pragma unroll
    for (int j = 0; j < 4; ++j) {
        int b = tx * 4 + j;
        int v0 = m0 + ty * 4;
        float4 w;
        w.x = acc[0][j] + bias[v0 + 0];
        w.y = acc[1][j] + bias[v0 + 1];
        w.z = acc[2][j] + bias[v0 + 2];
        w.w = acc[3][j] + bias[v0 + 3];
        *(float4*)&outp[(size_t)b * V + v0] = w;
    }
}

// ---------------------------------------------------------------------------
extern "C" void kernel_launch(void* const* d_in, const int* in_sizes, int n_in,
                              void* d_out, int out_size, void* d_ws, size_t ws_size,
                              hipStream_t stream)
{
    const int*   x     = (const int*)d_in[0];
    const float* hdec  = (const float*)d_in[1];
    const float* enc   = (const float*)d_in[2];
    const float* h0    = (const float*)d_in[3];
    const float* c0    = (const float*)d_in[4];
    const float* emb   = (const float*)d_in[5];
    const float* w_ih1 = (const float*)d_in[6];
    const float* w_hh1 = (const float*)d_in[7];
    const float* b_ih1 = (const float*)d_in[8];
    const float* b_hh1 = (const float*)d_in[9];
    const float* w_ih  = (const float*)d_in[10];
    // d_in[11] = w_hh: multiplied by zero hidden state in layers 2-4 -> skipped
    const float* b_ih  = (const float*)d_in[12];
    const float* b_hh  = (const float*)d_in[13];
    const float* fc_w  = (const float*)d_in[14];
    const float* fc_b  = (const float*)d_in[15];

    float* out = (float*)d_out;
    float* ws  = (float*)d_ws;

    float* m_part   = ws;                                // 2048
    float* l_part   = ws + 2048;                         // 2048
    float* acc_part = ws + 4096;                         // 64*32*512
    float* inp_t    = acc_part + (size_t)B * NCHUNK * H; // 1280*64
    float* zA       = inp_t + 1280 * B;                  // 512*64
    float* zB       = zA + H * B;                        // 512*64

    float* out_h = out + (size_t)B * V;
    float* out_c = out_h + (size_t)B * H;

    // 1) attention (enc read once, 268 MB)
    attn_part_kernel<<<512, 256, 0, stream>>>(hdec, enc, m_part, l_part, acc_part);
    combine_kernel<<<64, 256, 0, stream>>>(m_part, l_part, acc_part, x, emb, h0, inp_t);

    // 2) LSTM layer 1: K = 768 (w_ih1) | 512 (w_hh1) = 1280, real c0
    lstm_fused_kernel<<<128, 256, 0, stream>>>(
        w_ih1, 768, 768, w_hh1, 512, 1280, inp_t,
        b_ih1, b_hh1, c0, zA, nullptr, nullptr);

    // 3) LSTM layers 2-4 (zero h/c: only w_ih contributes), K = 512
    lstm_fused_kernel<<<128, 256, 0, stream>>>(
        w_ih + 0 * (size_t)2048 * H, 512, 512, nullptr, 0, 512, zA,
        b_ih + 0 * 2048, b_hh + 0 * 2048, nullptr, zB, nullptr, nullptr);
    lstm_fused_kernel<<<128, 256, 0, stream>>>(
        w_ih + 1 * (size_t)2048 * H, 512, 512, nullptr, 0, 512, zB,
        b_ih + 1 * 2048, b_hh + 1 * 2048, nullptr, zA, nullptr, nullptr);
    lstm_fused_kernel<<<128, 256, 0, stream>>>(
        w_ih + 2 * (size_t)2048 * H, 512, 512, nullptr, 0, 512, zA,
        b_ih + 2 * 2048, b_hh + 2 * 2048, nullptr, zB, out_h, out_c);

    // 4) logits = zB^T @ fc_w^T + fc_b  (BM=64, 500 blocks, 2-4 blocks/CU)
    fc_gemm_kernel<<<500, 256, 0, stream>>>(fc_w, zB, out, fc_b);
}